// Round 6
// baseline (391.287 us; speedup 1.0000x reference)
//
#include <hip/hip_runtime.h>
#include <hip/hip_bf16.h>
#include <stdint.h>

#define D_MODEL 1024
#define S_LEN   4096
#define BATCH   4
#define HEADS   16
#define DEPTH   64
#define ROWS    (BATCH*S_LEN)   // 16384
#define EPS_K_F 1e-6f
#define EPS_LN_F 1e-6f

typedef __attribute__((ext_vector_type(8))) short short8;
typedef __attribute__((ext_vector_type(4))) float f32x4;

__device__ __forceinline__ unsigned short f2bf(float f) {
  union { float f; unsigned u; } x; x.f = f;
  unsigned r = x.u + 0x7FFF + ((x.u >> 16) & 1);
  return (unsigned short)(r >> 16);
}
__device__ __forceinline__ float bf2f(unsigned short b) {
  union { unsigned u; float f; } x; x.u = ((unsigned)b) << 16;
  return x.f;
}
__device__ __forceinline__ void gload16(const void* g, void* l) {
  __builtin_amdgcn_global_load_lds(
      (const __attribute__((address_space(1))) void*)g,
      (__attribute__((address_space(3))) void*)l, 16, 0, 0);
}

// ---------------- f32 -> bf16 convert ----------------
__global__ __launch_bounds__(256) void cvt_f32_bf16_k(
    const float* __restrict__ in, unsigned short* __restrict__ out, int n4) {
  int i = blockIdx.x * 256 + threadIdx.x;
  if (i < n4) {
    float4 v = ((const float4*)in)[i];
    ushort4 o;
    o.x = f2bf(v.x); o.y = f2bf(v.y); o.z = f2bf(v.z); o.w = f2bf(v.w);
    ((ushort4*)out)[i] = o;
  }
}

// ---------------- weight transpose + convert: W[K,N] f32 -> Wt[N,K] bf16 ----
__global__ __launch_bounds__(256) void wtrans_k(
    const float* __restrict__ W, unsigned short* __restrict__ Wt) {
  __shared__ float tile[32][33];
  int n0 = blockIdx.x * 32, k0 = blockIdx.y * 32;
  int tx = threadIdx.x & 31, ty = threadIdx.x >> 5;
  #pragma unroll
  for (int i = 0; i < 32; i += 8)
    tile[ty + i][tx] = W[(size_t)(k0 + ty + i) * D_MODEL + n0 + tx];
  __syncthreads();
  #pragma unroll
  for (int i = 0; i < 32; i += 8)
    Wt[(size_t)(n0 + ty + i) * D_MODEL + k0 + tx] = f2bf(tile[tx][ty + i]);
}

// ---------------- bf16 GEMM 256x256 tile, 8 waves, counted-vmcnt pipeline ---
// A[M,K] @ Bt[N,K]^T -> Cb[M,N] bf16 (+bias), + per-(row,64col) LN partials.
// BK=32, 4 LDS slots per tensor (4 x 16KB x 2 = 128 KB total), prefetch
// depth 3 K-tiles. End-of-tile wait is vmcnt(8) in steady state (2 tiles =
// 8 gload_lds stay in flight across the barrier), vmcnt(4)/vmcnt(0) tail.
// LDS swizzle: (r,k) at r*32 + ((k>>3 ^ ((r>>1)&3))<<3) + (k&7); staging
// keeps LDS dest linear and inverse-XORs the per-lane global source.
// grid: 1D 256 blocks = (M/256)*(N/256); XCD-swizzled (N==1024 -> 4 col
// tiles; a row-panel's 4 col-tiles land on one XCD: xcd = p&7 = rb&7).
__global__ __launch_bounds__(512, 2) void gemm_bt_k(
    const unsigned short* __restrict__ A,
    const unsigned short* __restrict__ Bt,
    unsigned short* __restrict__ Cb,
    float* __restrict__ psum, float* __restrict__ psq,
    const float* __restrict__ bias,
    int M, int N, int K) {
  __shared__ unsigned short Al[4][256 * 32];
  __shared__ unsigned short Bl[4][256 * 32];
  int t = threadIdx.x;
  int lane = t & 63, wid = t >> 6;
  int wr = wid >> 2, wcn = wid & 3;        // 2 x 4 wave grid
  int l15 = lane & 15, lhi = lane >> 4;
  int p = blockIdx.x;
  int cb = (p >> 3) & 3;                   // col tile 0..3
  int rb = (p & 7) | ((p >> 5) << 3);      // row tile 0..63
  size_t m0 = (size_t)rb * 256, n0 = (size_t)cb * 256;
  f32x4 acc[8][4] = {};

  const int KT = K >> 5;                   // 32 K-tiles of 32

#define STAGE_TILE(tile_) do {                                              \
    int kof_ = (tile_) << 5; int slot_ = (tile_) & 3;                       \
    _Pragma("unroll")                                                       \
    for (int rnd = 0; rnd < 2; ++rnd) {                                     \
      int idx = rnd * 512 + t; int r_ = idx >> 2, cl_ = idx & 3;            \
      int cg_ = cl_ ^ ((r_ >> 1) & 3);                                      \
      gload16(A + (m0 + r_) * (size_t)K + kof_ + cg_ * 8,                   \
              &Al[slot_][idx * 8]);                                         \
    }                                                                       \
    _Pragma("unroll")                                                       \
    for (int rnd = 0; rnd < 2; ++rnd) {                                     \
      int idx = rnd * 512 + t; int r_ = idx >> 2, cl_ = idx & 3;            \
      int cg_ = cl_ ^ ((r_ >> 1) & 3);                                      \
      gload16(Bt + (n0 + r_) * (size_t)K + kof_ + cg_ * 8,                  \
              &Bl[slot_][idx * 8]);                                         \
    }                                                                       \
  } while (0)

  // prologue: stage tiles 0..2 (12 loads); wait tile 0 (vmcnt(8))
  STAGE_TILE(0);
  STAGE_TILE(1);
  STAGE_TILE(2);
  asm volatile("s_waitcnt vmcnt(8)" ::: "memory");
  __builtin_amdgcn_s_barrier();
  __builtin_amdgcn_sched_barrier(0);

  for (int kt = 0; kt < KT; ++kt) {
    int slot = kt & 3;
    if (kt + 3 < KT) STAGE_TILE(kt + 3);
    __builtin_amdgcn_sched_barrier(0);
    // B fragments (shared by both m-half phases)
    short8 bfr[4];
    #pragma unroll
    for (int n = 0; n < 4; ++n) {
      int rr = wcn * 64 + n * 16 + l15;
      bfr[n] = *(const short8*)&Bl[slot][rr * 32 + ((lhi ^ ((rr >> 1) & 3)) << 3)];
    }
    #pragma unroll
    for (int mh = 0; mh < 2; ++mh) {
      short8 af[4];
      #pragma unroll
      for (int m = 0; m < 4; ++m) {
        int rr = wr * 128 + (mh * 4 + m) * 16 + l15;
        af[m] = *(const short8*)&Al[slot][rr * 32 + ((lhi ^ ((rr >> 1) & 3)) << 3)];
      }
      asm volatile("s_waitcnt lgkmcnt(0)" ::: "memory");
      __builtin_amdgcn_sched_barrier(0);
      __builtin_amdgcn_s_setprio(1);
      #pragma unroll
      for (int m = 0; m < 4; ++m)
        #pragma unroll
        for (int n = 0; n < 4; ++n)
          acc[mh * 4 + m][n] = __builtin_amdgcn_mfma_f32_16x16x32_bf16(
              af[m], bfr[n], acc[mh * 4 + m][n], 0, 0, 0);
      __builtin_amdgcn_s_setprio(0);
    }
    if (kt + 1 < KT) {
      if (kt + 4 <= KT - 1)
        asm volatile("s_waitcnt vmcnt(8)" ::: "memory");
      else if (kt + 3 == KT - 1)
        asm volatile("s_waitcnt vmcnt(4)" ::: "memory");
      else
        asm volatile("s_waitcnt vmcnt(0)" ::: "memory");
      __builtin_amdgcn_s_barrier();
      __builtin_amdgcn_sched_barrier(0);
    }
  }
#undef STAGE_TILE

  // bias into acc first (stats must include bias, like reference)
  if (bias) {
    float bv[4];
    #pragma unroll
    for (int n = 0; n < 4; ++n)
      bv[n] = bias[(int)n0 + wcn * 64 + n * 16 + l15];
    #pragma unroll
    for (int m = 0; m < 8; ++m)
      #pragma unroll
      for (int n = 0; n < 4; ++n)
        #pragma unroll
        for (int j = 0; j < 4; ++j)
          acc[m][n][j] += bv[n];
  }

  // per-row partial sum / sumsq over this wave's 64 cols
  int seg = (int)(n0 >> 6) + wcn;          // 0..15
  #pragma unroll
  for (int m = 0; m < 8; ++m) {
    float s[4], s2[4];
    #pragma unroll
    for (int j = 0; j < 4; ++j) {
      float a = 0.f, b = 0.f;
      #pragma unroll
      for (int n = 0; n < 4; ++n) {
        float x = acc[m][n][j];
        a += x; b += x * x;
      }
      s[j] = a; s2[j] = b;
    }
    #pragma unroll
    for (int off = 1; off < 16; off <<= 1) {
      #pragma unroll
      for (int j = 0; j < 4; ++j) {
        s[j]  += __shfl_xor(s[j],  off);
        s2[j] += __shfl_xor(s2[j], off);
      }
    }
    if (l15 == 0) {
      #pragma unroll
      for (int j = 0; j < 4; ++j) {
        int rg = (int)m0 + wr * 128 + m * 16 + lhi * 4 + j;
        psum[rg * 16 + seg] = s[j];
        psq [rg * 16 + seg] = s2[j];
      }
    }
  }

  // bf16 C write
  #pragma unroll
  for (int m = 0; m < 8; ++m)
    #pragma unroll
    for (int j = 0; j < 4; ++j) {
      size_t row = m0 + wr * 128 + m * 16 + lhi * 4 + j;
      #pragma unroll
      for (int n = 0; n < 4; ++n) {
        int col = (int)n0 + wcn * 64 + n * 16 + l15;
        Cb[row * N + col] = f2bf(acc[m][n][j]);
      }
    }
}

// ---------------- LN + activation from bf16 C + partials -> bf16 ------------
// mode 0: relu(ln)+eps ; mode 1: (relu(ln)+eps)*mask ; mode 2: ln*mask
__global__ __launch_bounds__(256) void ln_act_k(
    const unsigned short* __restrict__ Cb,
    const float* __restrict__ psum, const float* __restrict__ psq,
    const float* __restrict__ gamma, const float* __restrict__ beta,
    const float* __restrict__ mask,
    unsigned short* __restrict__ out, int mode) {
  int row = blockIdx.x;
  int t = threadIdx.x;
  float s = 0.f, s2 = 0.f;
  #pragma unroll
  for (int i = 0; i < 16; ++i) { s += psum[row * 16 + i]; s2 += psq[row * 16 + i]; }
  float mean = s * (1.f / D_MODEL);
  float var = s2 * (1.f / D_MODEL) - mean * mean;
  float rstd = rsqrtf(var + EPS_LN_F);
  float mk = (mode > 0) ? mask[row] : 1.f;
  ushort4 cv = ((const ushort4*)(Cb + (size_t)row * D_MODEL))[t];
  float4 gv = ((const float4*)gamma)[t];
  float4 bv = ((const float4*)beta)[t];
  float av[4] = {bf2f(cv.x), bf2f(cv.y), bf2f(cv.z), bf2f(cv.w)};
  float g4[4] = {gv.x, gv.y, gv.z, gv.w};
  float b4[4] = {bv.x, bv.y, bv.z, bv.w};
  unsigned short ov[4];
  #pragma unroll
  for (int j = 0; j < 4; ++j) {
    float ln = (av[j] - mean) * rstd * g4[j] + b4[j];
    if (mode == 0)      ln = fmaxf(ln, 0.f) + EPS_K_F;
    else if (mode == 1) ln = (fmaxf(ln, 0.f) + EPS_K_F) * mk;
    else                ln = ln * mk;
    ov[j] = f2bf(ln);
  }
  ushort4 o; o.x = ov[0]; o.y = ov[1]; o.z = ov[2]; o.w = ov[3];
  ((ushort4*)(out + (size_t)row * D_MODEL))[t] = o;
}

// ---------------- final LayerNorm from bf16 C + partials -> f32 out ---------
__global__ __launch_bounds__(256) void ln_final_k(
    const unsigned short* __restrict__ Cb,
    const float* __restrict__ psum, const float* __restrict__ psq,
    const float* __restrict__ gamma, const float* __restrict__ beta,
    float* __restrict__ out) {
  int row = blockIdx.x;
  int t = threadIdx.x;
  float s = 0.f, s2 = 0.f;
  #pragma unroll
  for (int i = 0; i < 16; ++i) { s += psum[row * 16 + i]; s2 += psq[row * 16 + i]; }
  float mean = s * (1.f / D_MODEL);
  float var = s2 * (1.f / D_MODEL) - mean * mean;
  float rstd = rsqrtf(var + EPS_LN_F);
  ushort4 cv = ((const ushort4*)(Cb + (size_t)row * D_MODEL))[t];
  float4 gv = ((const float4*)gamma)[t];
  float4 bv = ((const float4*)beta)[t];
  float4 w;
  w.x = (bf2f(cv.x) - mean) * rstd * gv.x + bv.x;
  w.y = (bf2f(cv.y) - mean) * rstd * gv.y + bv.y;
  w.z = (bf2f(cv.z) - mean) * rstd * gv.z + bv.z;
  w.w = (bf2f(cv.w) - mean) * rstd * gv.w + bv.w;
  ((float4*)(out + (size_t)row * D_MODEL))[t] = w;
}

// ---------------- KV via MFMA with swizzled-LDS transpose -------------------
__global__ __launch_bounds__(256) void kv_mfma_k(
    const unsigned short* __restrict__ Kp, const unsigned short* __restrict__ Vp,
    float* __restrict__ part, float* __restrict__ kspart) {
  __shared__ unsigned short Kl[4096];
  __shared__ unsigned short Vl[4096];
  int bh = blockIdx.y, chunk = blockIdx.x;   // chunk 0..7, 512 n each
  int b_ = bh >> 4, h = bh & 15;
  int t = threadIdx.x, lane = t & 63, w = t >> 6;
  int l15 = lane & 15, g = lane >> 4;        // g in 0..3

  int sn = t >> 2, sd16 = t & 3;
  int sc = sd16 ^ ((sn >> 3) & 3);
  size_t goff = (size_t)sn * D_MODEL + h * DEPTH + sd16 * 16;
  int ldst = sn * 64 + sc * 16;

  short8 ones;
  #pragma unroll
  for (int i = 0; i < 8; ++i) ones[i] = (short)0x3F80;

  f32x4 acc[4] = {};
  f32x4 ks = {};

  int baseA = ((w ^ g) << 4) + l15;
  int baseB0 = ((0 ^ g) << 4) + l15;
  int baseB1 = ((1 ^ g) << 4) + l15;
  int baseB2 = ((2 ^ g) << 4) + l15;
  int baseB3 = ((3 ^ g) << 4) + l15;

  size_t rowbase = ((size_t)b_ * S_LEN + (size_t)chunk * 512) * D_MODEL;
  for (int tile = 0; tile < 8; ++tile) {
    const unsigned short* kg = Kp + rowbase + (size_t)tile * 64 * D_MODEL + goff;
    const unsigned short* vg = Vp + rowbase + (size_t)tile * 64 * D_MODEL + goff;
    uint4 ra = *(const uint4*)kg;
    uint4 rb = *(const uint4*)(kg + 8);
    uint4 rc = *(const uint4*)vg;
    uint4 rd = *(const uint4*)(vg + 8);
    __syncthreads();
    *(uint4*)&Kl[ldst]     = ra;
    *(uint4*)&Kl[ldst + 8] = rb;
    *(uint4*)&Vl[ldst]     = rc;
    *(uint4*)&Vl[ldst + 8] = rd;
    __syncthreads();
    #pragma unroll
    for (int kk = 0; kk < 2; ++kk) {
      int nb = (kk * 32 + g * 8) * 64;
      short8 af, bf0, bf1, bf2, bf3;
      #pragma unroll
      for (int i = 0; i < 8; ++i) {
        int rowoff = nb + i * 64;
        af[i]  = (short)Kl[rowoff + baseA];
        bf0[i] = (short)Vl[rowoff + baseB0];
        bf1[i] = (short)Vl[rowoff + baseB1];
        bf2[i] = (short)Vl[rowoff + baseB2];
        bf3[i] = (short)Vl[rowoff + baseB3];
      }
      acc[0] = __builtin_amdgcn_mfma_f32_16x16x32_bf16(af, bf0, acc[0], 0, 0, 0);
      acc[1] = __builtin_amdgcn_mfma_f32_16x16x32_bf16(af, bf1, acc[1], 0, 0, 0);
      acc[2] = __builtin_amdgcn_mfma_f32_16x16x32_bf16(af, bf2, acc[2], 0, 0, 0);
      acc[3] = __builtin_amdgcn_mfma_f32_16x16x32_bf16(af, bf3, acc[3], 0, 0, 0);
      ks     = __builtin_amdgcn_mfma_f32_16x16x32_bf16(af, ones, ks, 0, 0, 0);
    }
  }
  float* pp = part + ((size_t)bh * 8 + chunk) * 4096;
  #pragma unroll
  for (int nf = 0; nf < 4; ++nf)
    #pragma unroll
    for (int r = 0; r < 4; ++r)
      pp[(16 * w + 4 * g + r) * 64 + 16 * nf + l15] = acc[nf][r];
  if (l15 == 0) {
    #pragma unroll
    for (int r = 0; r < 4; ++r)
      kspart[((size_t)bh * 8 + chunk) * 64 + 16 * w + 4 * g + r] = ks[r];
  }
}

// ---------------- KV reduce -> KV^T bf16 ([e][d]) + ksum f32 ----------------
__global__ __launch_bounds__(256) void kv_reduce_k(
    const float* __restrict__ part, const float* __restrict__ kspart,
    unsigned short* __restrict__ KVT, float* __restrict__ ksum) {
  int bh = blockIdx.x, t = threadIdx.x;
  for (int idx = t; idx < 4096; idx += 256) {
    int d = idx >> 6, e = idx & 63;
    float s = 0.f;
    #pragma unroll
    for (int c = 0; c < 8; ++c)
      s += part[((size_t)bh * 8 + c) * 4096 + d * 64 + e];
    KVT[(size_t)bh * 4096 + e * 64 + d] = f2bf(s);
  }
  if (t < 64) {
    float s = 0.f;
    #pragma unroll
    for (int c = 0; c < 8; ++c) s += kspart[((size_t)bh * 8 + c) * 64 + t];
    ksum[bh * 64 + t] = s;
  }
}

// ---------------- att = (q' @ KV) * z, written in the reference's reshape ---
__global__ __launch_bounds__(256) void att_k(
    const unsigned short* __restrict__ Qp, const unsigned short* __restrict__ KVT,
    const float* __restrict__ ksum, unsigned short* __restrict__ att) {
  __shared__ unsigned short Ql[128 * 64];
  __shared__ unsigned short Kl[64 * 64];
  __shared__ float ksl[64];
  __shared__ float zl[128];
  int bh = blockIdx.y;
  int b = bh >> 4, h = bh & 15;
  int r0 = blockIdx.x * 128;
  int t = threadIdx.x, lane = t & 63, wid = t >> 6;
  int l15 = lane & 15, lhi = lane >> 4;
  #pragma unroll
  for (int i = 0; i < 4; ++i) {
    int cid = i * 256 + t;
    int r = cid >> 3, c8 = cid & 7;
    gload16(Qp + ((size_t)(b * S_LEN + r0 + r)) * D_MODEL + h * DEPTH + c8 * 8,
            &Ql[cid * 8]);
  }
  #pragma unroll
  for (int i = 0; i < 2; ++i) {
    int cid = i * 256 + t;
    gload16(KVT + (size_t)bh * 4096 + cid * 8, &Kl[cid * 8]);
  }
  if (t < 64) ksl[t] = ksum[bh * 64 + t];
  asm volatile("s_waitcnt vmcnt(0)" ::: "memory");
  __syncthreads();
  {
    int r = t >> 1, half = t & 1;
    float s = 0.f;
    #pragma unroll
    for (int j = 0; j < 32; ++j)
      s += bf2f(Ql[r * 64 + half * 32 + j]) * ksl[half * 32 + j];
    s += __shfl_xor(s, 1);
    if (half == 0) zl[r] = 1.f / (s + EPS_K_F);
  }
  __syncthreads();
  f32x4 acc[2][4] = {};
  #pragma unroll
  for (int kk = 0; kk < 2; ++kk) {
    short8 af[2], bfr[4];
    #pragma unroll
    for (int m = 0; m < 2; ++m)
      af[m] = *(const short8*)&Ql[(wid * 32 + m * 16 + l15) * 64 + kk * 32 + lhi * 8];
    #pragma unroll
    for (int n = 0; n < 4; ++n)
      bfr[n] = *(const short8*)&Kl[(n * 16 + l15) * 64 + kk * 32 + lhi * 8];
    #pragma unroll
    for (int m = 0; m < 2; ++m)
      #pragma unroll
      for (int n = 0; n < 4; ++n)
        acc[m][n] = __builtin_amdgcn_mfma_f32_16x16x32_bf16(af[m], bfr[n], acc[m][n], 0, 0, 0);
  }
  #pragma unroll
  for (int m = 0; m < 2; ++m)
    #pragma unroll
    for (int j = 0; j < 4; ++j) {
      int rl = wid * 32 + m * 16 + lhi * 4 + j;
      int n = r0 + rl;
      float z = zl[rl];
      #pragma unroll
      for (int nf = 0; nf < 4; ++nf) {
        int ee = nf * 16 + l15;
        size_t orow = (size_t)b * S_LEN + h * 256 + (n >> 4);
        int ocol = (n & 15) * 64 + ee;
        att[orow * D_MODEL + ocol] = f2bf(acc[m][nf][j] * z);
      }
    }
}

extern "C" void kernel_launch(void* const* d_in, const int* in_sizes, int n_in,
                              void* d_out, int out_size, void* d_ws, size_t ws_size,
                              hipStream_t stream) {
  (void)in_sizes; (void)n_in; (void)out_size; (void)ws_size;
  const float* q     = (const float*)d_in[0];
  const float* k     = (const float*)d_in[1];
  const float* v     = (const float*)d_in[2];
  const float* mask  = (const float*)d_in[3];
  const float* wq    = (const float*)d_in[4];
  const float* wk    = (const float*)d_in[5];
  const float* wv    = (const float*)d_in[6];
  const float* gamma = (const float*)d_in[7];
  const float* beta  = (const float*)d_in[8];
  const float* dw    = (const float*)d_in[9];
  const float* db    = (const float*)d_in[10];
  float* out = (float*)d_out;

  char* ws = (char*)d_ws;
  unsigned short* Xb  = (unsigned short*)(ws);               // 33.5 MB
  unsigned short* Qp  = (unsigned short*)(ws + 33554432);    // also dense-C after att
  unsigned short* Kp  = (unsigned short*)(ws + 67108864);
  unsigned short* Vp  = (unsigned short*)(ws + 100663296);
  unsigned short* WqT = (unsigned short*)(ws + 134217728);
  unsigned short* WkT = WqT + 1048576;
  unsigned short* WvT = WkT + 1048576;
  unsigned short* WdT = WvT + 1048576;
  float* part   = (float*)(ws);             // aliases Xb (dead mid-pipeline)
  float* kspart = (float*)(ws + 8388608);
  unsigned short* KVT = (unsigned short*)(ws + 142606336);
  float* ksum = (float*)(ws + 143130624);
  float* psum = (float*)(ws + 143654912);   // 16384*16 f32 = 1 MB
  float* psq  = (float*)(ws + 144703488);   // 1 MB
  unsigned short* Cqkv = (unsigned short*)d_out;   // bf16 C scratch (32 MB of 67)
  unsigned short* Cd   = Qp;                       // dense C: Qp dead after att_k

  dim3 b256(256);
  dim3 b512(512);
  int n4 = ROWS * D_MODEL / 4;
  dim3 cvtg(n4 / 256);
  dim3 wtg(32, 32);
  dim3 gemmg(256);            // (M/256)*(N/256), XCD-swizzled in-kernel
  dim3 lng(ROWS);

  wtrans_k<<<wtg, b256, 0, stream>>>(wq, WqT);
  wtrans_k<<<wtg, b256, 0, stream>>>(wk, WkT);
  wtrans_k<<<wtg, b256, 0, stream>>>(wv, WvT);
  wtrans_k<<<wtg, b256, 0, stream>>>(dw, WdT);

  cvt_f32_bf16_k<<<cvtg, b256, 0, stream>>>(q, Xb, n4);
  gemm_bt_k<<<gemmg, b512, 0, stream>>>(Xb, WqT, Cqkv, psum, psq, nullptr, ROWS, D_MODEL, D_MODEL);
  ln_act_k<<<lng, b256, 0, stream>>>(Cqkv, psum, psq, gamma, beta, nullptr, Qp, 0);

  cvt_f32_bf16_k<<<cvtg, b256, 0, stream>>>(k, Xb, n4);
  gemm_bt_k<<<gemmg, b512, 0, stream>>>(Xb, WkT, Cqkv, psum, psq, nullptr, ROWS, D_MODEL, D_MODEL);
  ln_act_k<<<lng, b256, 0, stream>>>(Cqkv, psum, psq, gamma, beta, mask, Kp, 1);

  cvt_f32_bf16_k<<<cvtg, b256, 0, stream>>>(v, Xb, n4);
  gemm_bt_k<<<gemmg, b512, 0, stream>>>(Xb, WvT, Cqkv, psum, psq, nullptr, ROWS, D_MODEL, D_MODEL);
  ln_act_k<<<lng, b256, 0, stream>>>(Cqkv, psum, psq, gamma, beta, mask, Vp, 2);

  kv_mfma_k<<<dim3(8, 64), b256, 0, stream>>>(Kp, Vp, part, kspart);
  kv_reduce_k<<<dim3(64), b256, 0, stream>>>(part, kspart, KVT, ksum);
  att_k<<<dim3(32, 64), b256, 0, stream>>>(Qp, KVT, ksum, Xb);

  gemm_bt_k<<<gemmg, b512, 0, stream>>>(Xb, WdT, Cd, psum, psq, db, ROWS, D_MODEL, D_MODEL);
  ln_final_k<<<lng, b256, 0, stream>>>(Cd, psum, psq, gamma, beta, out);
}

// Round 7
// 372.768 us; speedup vs baseline: 1.0497x; 1.0497x over previous
//
#include <hip/hip_runtime.h>
#include <hip/hip_bf16.h>
#include <stdint.h>

#define D_MODEL 1024
#define S_LEN   4096
#define BATCH   4
#define HEADS   16
#define DEPTH   64
#define ROWS    (BATCH*S_LEN)   // 16384
#define EPS_K_F 1e-6f
#define EPS_LN_F 1e-6f

typedef __attribute__((ext_vector_type(8))) short short8;
typedef __attribute__((ext_vector_type(4))) float f32x4;

__device__ __forceinline__ unsigned short f2bf(float f) {
  union { float f; unsigned u; } x; x.f = f;
  unsigned r = x.u + 0x7FFF + ((x.u >> 16) & 1);
  return (unsigned short)(r >> 16);
}
__device__ __forceinline__ float bf2f(unsigned short b) {
  union { unsigned u; float f; } x; x.u = ((unsigned)b) << 16;
  return x.f;
}
__device__ __forceinline__ void gload16(const void* g, void* l) {
  __builtin_amdgcn_global_load_lds(
      (const __attribute__((address_space(1))) void*)g,
      (__attribute__((address_space(3))) void*)l, 16, 0, 0);
}

// ---------------- weight transpose + convert: W[K,N] f32 -> Wt[N,K] bf16 ----
__global__ __launch_bounds__(256) void wtrans_k(
    const float* __restrict__ W, unsigned short* __restrict__ Wt) {
  __shared__ float tile[32][33];
  int n0 = blockIdx.x * 32, k0 = blockIdx.y * 32;
  int tx = threadIdx.x & 31, ty = threadIdx.x >> 5;
  #pragma unroll
  for (int i = 0; i < 32; i += 8)
    tile[ty + i][tx] = W[(size_t)(k0 + ty + i) * D_MODEL + n0 + tx];
  __syncthreads();
  #pragma unroll
  for (int i = 0; i < 32; i += 8)
    Wt[(size_t)(n0 + ty + i) * D_MODEL + k0 + tx] = f2bf(tile[tx][ty + i]);
}

// ===== shared GEMM pieces ===================================================
// 256x256 tile, 8 waves (2M x 4N), BK=64, 2 LDS buffers, R5 schedule:
// issue next-tile staging at tile start, compute 4 sub-phases (kk x mh) with
// bfr hoisted per kk, drain vmcnt+lgkm and barrier once per K-tile.
// LDS swizzle: (r,k) chunk (k>>3) stored at slot (k>>3)^(r&7); frag read
// uses cx = (kk*4+lhi) ^ (l15&7).
// grid: 1D 256 = (M/256)*(N/256); XCD swizzle: cb=(p>>3)&3, rb=(p&7)|((p>>5)<<3).

#define GEMM_EPILOGUE(HASBIAS)                                               \
  if (HASBIAS) {                                                             \
    float bv[4];                                                             \
    _Pragma("unroll")                                                        \
    for (int n = 0; n < 4; ++n)                                              \
      bv[n] = bias[(int)n0 + wcn * 64 + n * 16 + l15];                       \
    _Pragma("unroll")                                                        \
    for (int m = 0; m < 8; ++m)                                              \
      _Pragma("unroll")                                                      \
      for (int n = 0; n < 4; ++n)                                            \
        _Pragma("unroll")                                                    \
        for (int j = 0; j < 4; ++j)                                          \
          acc[m][n][j] += bv[n];                                             \
  }                                                                          \
  int seg = (int)(n0 >> 6) + wcn;                                            \
  _Pragma("unroll")                                                          \
  for (int m = 0; m < 8; ++m) {                                              \
    float s[4], s2[4];                                                       \
    _Pragma("unroll")                                                        \
    for (int j = 0; j < 4; ++j) {                                            \
      float a = 0.f, b = 0.f;                                                \
      _Pragma("unroll")                                                      \
      for (int n = 0; n < 4; ++n) { float x = acc[m][n][j]; a += x; b += x*x; } \
      s[j] = a; s2[j] = b;                                                   \
    }                                                                        \
    _Pragma("unroll")                                                        \
    for (int off = 1; off < 16; off <<= 1) {                                 \
      _Pragma("unroll")                                                      \
      for (int j = 0; j < 4; ++j) {                                          \
        s[j]  += __shfl_xor(s[j],  off);                                     \
        s2[j] += __shfl_xor(s2[j], off);                                     \
      }                                                                      \
    }                                                                        \
    if (l15 == 0) {                                                          \
      _Pragma("unroll")                                                      \
      for (int j = 0; j < 4; ++j) {                                          \
        int rg = (int)m0 + wr * 128 + m * 16 + lhi * 4 + j;                  \
        psum[rg * 16 + seg] = s[j];                                          \
        psq [rg * 16 + seg] = s2[j];                                         \
      }                                                                      \
    }                                                                        \
  }                                                                          \
  _Pragma("unroll")                                                          \
  for (int m = 0; m < 8; ++m)                                                \
    _Pragma("unroll")                                                        \
    for (int j = 0; j < 4; ++j) {                                            \
      size_t row = m0 + wr * 128 + m * 16 + lhi * 4 + j;                     \
      _Pragma("unroll")                                                      \
      for (int n = 0; n < 4; ++n) {                                          \
        int col = (int)n0 + wcn * 64 + n * 16 + l15;                         \
        Cb[row * N + col] = f2bf(acc[m][n][j]);                              \
      }                                                                      \
    }

#define GEMM_COMPUTE_TILE(ABUF, BBUF)                                        \
  _Pragma("unroll")                                                          \
  for (int kk = 0; kk < 2; ++kk) {                                           \
    short8 bfr[4];                                                           \
    _Pragma("unroll")                                                        \
    for (int n = 0; n < 4; ++n) {                                            \
      int rr = wcn * 64 + n * 16 + l15;                                      \
      int cx = (kk * 4 + lhi) ^ (l15 & 7);                                   \
      bfr[n] = *(const short8*)&(BBUF)[rr * 64 + cx * 8];                    \
    }                                                                        \
    _Pragma("unroll")                                                        \
    for (int mh = 0; mh < 2; ++mh) {                                         \
      short8 af[4];                                                          \
      _Pragma("unroll")                                                      \
      for (int m = 0; m < 4; ++m) {                                          \
        int rr = wr * 128 + (mh * 4 + m) * 16 + l15;                         \
        int cx = (kk * 4 + lhi) ^ (l15 & 7);                                 \
        af[m] = *(const short8*)&(ABUF)[rr * 64 + cx * 8];                   \
      }                                                                      \
      asm volatile("s_waitcnt lgkmcnt(0)" ::: "memory");                     \
      __builtin_amdgcn_sched_barrier(0);                                     \
      __builtin_amdgcn_s_setprio(1);                                         \
      _Pragma("unroll")                                                      \
      for (int m = 0; m < 4; ++m)                                            \
        _Pragma("unroll")                                                    \
        for (int n = 0; n < 4; ++n)                                          \
          acc[mh * 4 + m][n] = __builtin_amdgcn_mfma_f32_16x16x32_bf16(      \
              af[m], bfr[n], acc[mh * 4 + m][n], 0, 0, 0);                   \
      __builtin_amdgcn_s_setprio(0);                                         \
    }                                                                        \
  }

// ---------------- GEMM with fused f32->bf16 A-conversion (qkv projections) --
// A is f32 [M,K]; staged via regs (coalesced float4) + convert + swizzled
// ds_write_b64. B (weights, bf16 [N,K]) staged via global_load_lds.
__global__ __launch_bounds__(512, 2) void gemm_f32a_k(
    const float* __restrict__ Af,
    const unsigned short* __restrict__ Bt,
    unsigned short* __restrict__ Cb,
    float* __restrict__ psum, float* __restrict__ psq,
    int M, int N, int K) {
  __shared__ unsigned short Al[2][256 * 64];
  __shared__ unsigned short Bl[2][256 * 64];
  int t = threadIdx.x;
  int lane = t & 63, wid = t >> 6;
  int wr = wid >> 2, wcn = wid & 3;
  int l15 = lane & 15, lhi = lane >> 4;
  int p = blockIdx.x;
  int cb = (p >> 3) & 3;
  int rb = (p & 7) | ((p >> 5) << 3);
  size_t m0 = (size_t)rb * 256, n0 = (size_t)cb * 256;
  f32x4 acc[8][4] = {};

  const int KT = K >> 6;                 // 16 K-tiles of 64
  int arow = t >> 4;                     // 0..31 (row within 32-row group)
  int ac = t & 15;                       // 4-float column group
  int achunk = ((ac >> 1) ^ (arow & 7)); // swizzled 8-elem chunk slot
  int aldso = achunk * 8 + (ac & 1) * 4; // bf16 offset within row
  float4 areg[8];

#define LOAD_A(kof_) do {                                                    \
    _Pragma("unroll")                                                        \
    for (int j = 0; j < 8; ++j)                                              \
      areg[j] = *(const float4*)(Af + (m0 + j * 32 + arow) * (size_t)K +     \
                                 (kof_) + ac * 4);                           \
  } while (0)
#define WRITE_A(buf_) do {                                                   \
    _Pragma("unroll")                                                        \
    for (int j = 0; j < 8; ++j) {                                            \
      unsigned lo_ = (unsigned)f2bf(areg[j].x) |                             \
                     ((unsigned)f2bf(areg[j].y) << 16);                      \
      unsigned hi_ = (unsigned)f2bf(areg[j].z) |                             \
                     ((unsigned)f2bf(areg[j].w) << 16);                      \
      uint2 wv_; wv_.x = lo_; wv_.y = hi_;                                   \
      *(uint2*)&Al[buf_][(j * 32 + arow) * 64 + aldso] = wv_;                \
    }                                                                        \
  } while (0)
#define STAGE_B(kof_, buf_) do {                                             \
    _Pragma("unroll")                                                        \
    for (int sub = 0; sub < 4; ++sub) {                                      \
      int idx = sub * 512 + t; int r_ = idx >> 3, cl_ = idx & 7;             \
      int cg_ = cl_ ^ (r_ & 7);                                              \
      gload16(Bt + (n0 + r_) * (size_t)K + (kof_) + cg_ * 8,                 \
              &Bl[buf_][idx * 8]);                                           \
    }                                                                        \
  } while (0)

  // prologue: tile 0
  LOAD_A(0);
  STAGE_B(0, 0);
  WRITE_A(0);
  asm volatile("s_waitcnt vmcnt(0) lgkmcnt(0)" ::: "memory");
  __builtin_amdgcn_s_barrier();
  __builtin_amdgcn_sched_barrier(0);

  for (int kt = 0; kt < KT; ++kt) {
    int buf = kt & 1;
    if (kt + 1 < KT) {
      int kn = (kt + 1) << 6;
      LOAD_A(kn);
      STAGE_B(kn, buf ^ 1);
    }
    __builtin_amdgcn_sched_barrier(0);
    GEMM_COMPUTE_TILE(Al[buf], Bl[buf]);
    if (kt + 1 < KT) WRITE_A(buf ^ 1);
    asm volatile("s_waitcnt vmcnt(0) lgkmcnt(0)" ::: "memory");
    __builtin_amdgcn_s_barrier();
    __builtin_amdgcn_sched_barrier(0);
  }
#undef LOAD_A
#undef WRITE_A
#undef STAGE_B

  const float* bias = nullptr;
  GEMM_EPILOGUE(false)
}

// ---------------- GEMM with bf16 A (dense layer) ----------------------------
__global__ __launch_bounds__(512, 2) void gemm_bt_k(
    const unsigned short* __restrict__ A,
    const unsigned short* __restrict__ Bt,
    unsigned short* __restrict__ Cb,
    float* __restrict__ psum, float* __restrict__ psq,
    const float* __restrict__ bias,
    int M, int N, int K) {
  __shared__ unsigned short Al[2][256 * 64];
  __shared__ unsigned short Bl[2][256 * 64];
  int t = threadIdx.x;
  int lane = t & 63, wid = t >> 6;
  int wr = wid >> 2, wcn = wid & 3;
  int l15 = lane & 15, lhi = lane >> 4;
  int p = blockIdx.x;
  int cb = (p >> 3) & 3;
  int rb = (p & 7) | ((p >> 5) << 3);
  size_t m0 = (size_t)rb * 256, n0 = (size_t)cb * 256;
  f32x4 acc[8][4] = {};

  const int KT = K >> 6;

#define STAGE_AB(kof_, buf_) do {                                            \
    _Pragma("unroll")                                                        \
    for (int sub = 0; sub < 4; ++sub) {                                      \
      int idx = sub * 512 + t; int r_ = idx >> 3, cl_ = idx & 7;             \
      int cg_ = cl_ ^ (r_ & 7);                                              \
      gload16(A + (m0 + r_) * (size_t)K + (kof_) + cg_ * 8,                  \
              &Al[buf_][idx * 8]);                                           \
    }                                                                        \
    _Pragma("unroll")                                                        \
    for (int sub = 0; sub < 4; ++sub) {                                      \
      int idx = sub * 512 + t; int r_ = idx >> 3, cl_ = idx & 7;             \
      int cg_ = cl_ ^ (r_ & 7);                                              \
      gload16(Bt + (n0 + r_) * (size_t)K + (kof_) + cg_ * 8,                 \
              &Bl[buf_][idx * 8]);                                           \
    }                                                                        \
  } while (0)

  STAGE_AB(0, 0);
  asm volatile("s_waitcnt vmcnt(0)" ::: "memory");
  __builtin_amdgcn_s_barrier();
  __builtin_amdgcn_sched_barrier(0);

  for (int kt = 0; kt < KT; ++kt) {
    int buf = kt & 1;
    if (kt + 1 < KT) STAGE_AB((kt + 1) << 6, buf ^ 1);
    __builtin_amdgcn_sched_barrier(0);
    GEMM_COMPUTE_TILE(Al[buf], Bl[buf]);
    asm volatile("s_waitcnt vmcnt(0) lgkmcnt(0)" ::: "memory");
    __builtin_amdgcn_s_barrier();
    __builtin_amdgcn_sched_barrier(0);
  }
#undef STAGE_AB

  GEMM_EPILOGUE(bias != nullptr)
}

// ---------------- LN + activation from bf16 C + partials -> bf16 ------------
// mode 0: relu(ln)+eps ; mode 1: (relu(ln)+eps)*mask ; mode 2: ln*mask
__global__ __launch_bounds__(256) void ln_act_k(
    const unsigned short* __restrict__ Cb,
    const float* __restrict__ psum, const float* __restrict__ psq,
    const float* __restrict__ gamma, const float* __restrict__ beta,
    const float* __restrict__ mask,
    unsigned short* __restrict__ out, int mode) {
  int row = blockIdx.x;
  int t = threadIdx.x;
  float s = 0.f, s2 = 0.f;
  #pragma unroll
  for (int i = 0; i < 16; ++i) { s += psum[row * 16 + i]; s2 += psq[row * 16 + i]; }
  float mean = s * (1.f / D_MODEL);
  float var = s2 * (1.f / D_MODEL) - mean * mean;
  float rstd = rsqrtf(var + EPS_LN_F);
  float mk = (mode > 0) ? mask[row] : 1.f;
  ushort4 cv = ((const ushort4*)(Cb + (size_t)row * D_MODEL))[t];
  float4 gv = ((const float4*)gamma)[t];
  float4 bv = ((const float4*)beta)[t];
  float av[4] = {bf2f(cv.x), bf2f(cv.y), bf2f(cv.z), bf2f(cv.w)};
  float g4[4] = {gv.x, gv.y, gv.z, gv.w};
  float b4[4] = {bv.x, bv.y, bv.z, bv.w};
  unsigned short ov[4];
  #pragma unroll
  for (int j = 0; j < 4; ++j) {
    float ln = (av[j] - mean) * rstd * g4[j] + b4[j];
    if (mode == 0)      ln = fmaxf(ln, 0.f) + EPS_K_F;
    else if (mode == 1) ln = (fmaxf(ln, 0.f) + EPS_K_F) * mk;
    else                ln = ln * mk;
    ov[j] = f2bf(ln);
  }
  ushort4 o; o.x = ov[0]; o.y = ov[1]; o.z = ov[2]; o.w = ov[3];
  ((ushort4*)(out + (size_t)row * D_MODEL))[t] = o;
}

// ---------------- final LayerNorm from bf16 C + partials -> f32 out ---------
__global__ __launch_bounds__(256) void ln_final_k(
    const unsigned short* __restrict__ Cb,
    const float* __restrict__ psum, const float* __restrict__ psq,
    const float* __restrict__ gamma, const float* __restrict__ beta,
    float* __restrict__ out) {
  int row = blockIdx.x;
  int t = threadIdx.x;
  float s = 0.f, s2 = 0.f;
  #pragma unroll
  for (int i = 0; i < 16; ++i) { s += psum[row * 16 + i]; s2 += psq[row * 16 + i]; }
  float mean = s * (1.f / D_MODEL);
  float var = s2 * (1.f / D_MODEL) - mean * mean;
  float rstd = rsqrtf(var + EPS_LN_F);
  ushort4 cv = ((const ushort4*)(Cb + (size_t)row * D_MODEL))[t];
  float4 gv = ((const float4*)gamma)[t];
  float4 bv = ((const float4*)beta)[t];
  float4 w;
  w.x = (bf2f(cv.x) - mean) * rstd * gv.x + bv.x;
  w.y = (bf2f(cv.y) - mean) * rstd * gv.y + bv.y;
  w.z = (bf2f(cv.z) - mean) * rstd * gv.z + bv.z;
  w.w = (bf2f(cv.w) - mean) * rstd * gv.w + bv.w;
  ((float4*)(out + (size_t)row * D_MODEL))[t] = w;
}

// ---------------- KV via MFMA with swizzled-LDS transpose -------------------
__global__ __launch_bounds__(256) void kv_mfma_k(
    const unsigned short* __restrict__ Kp, const unsigned short* __restrict__ Vp,
    float* __restrict__ part, float* __restrict__ kspart) {
  __shared__ unsigned short Kl[4096];
  __shared__ unsigned short Vl[4096];
  int bh = blockIdx.y, chunk = blockIdx.x;   // chunk 0..7, 512 n each
  int b_ = bh >> 4, h = bh & 15;
  int t = threadIdx.x, lane = t & 63, w = t >> 6;
  int l15 = lane & 15, g = lane >> 4;        // g in 0..3

  int sn = t >> 2, sd16 = t & 3;
  int sc = sd16 ^ ((sn >> 3) & 3);
  size_t goff = (size_t)sn * D_MODEL + h * DEPTH + sd16 * 16;
  int ldst = sn * 64 + sc * 16;

  short8 ones;
  #pragma unroll
  for (int i = 0; i < 8; ++i) ones[i] = (short)0x3F80;

  f32x4 acc[4] = {};
  f32x4 ks = {};

  int baseA = ((w ^ g) << 4) + l15;
  int baseB0 = ((0 ^ g) << 4) + l15;
  int baseB1 = ((1 ^ g) << 4) + l15;
  int baseB2 = ((2 ^ g) << 4) + l15;
  int baseB3 = ((3 ^ g) << 4) + l15;

  size_t rowbase = ((size_t)b_ * S_LEN + (size_t)chunk * 512) * D_MODEL;
  for (int tile = 0; tile < 8; ++tile) {
    const unsigned short* kg = Kp + rowbase + (size_t)tile * 64 * D_MODEL + goff;
    const unsigned short* vg = Vp + rowbase + (size_t)tile * 64 * D_MODEL + goff;
    uint4 ra = *(const uint4*)kg;
    uint4 rb = *(const uint4*)(kg + 8);
    uint4 rc = *(const uint4*)vg;
    uint4 rd = *(const uint4*)(vg + 8);
    __syncthreads();
    *(uint4*)&Kl[ldst]     = ra;
    *(uint4*)&Kl[ldst + 8] = rb;
    *(uint4*)&Vl[ldst]     = rc;
    *(uint4*)&Vl[ldst + 8] = rd;
    __syncthreads();
    #pragma unroll
    for (int kk = 0; kk < 2; ++kk) {
      int nb = (kk * 32 + g * 8) * 64;
      short8 af, bf0, bf1, bf2, bf3;
      #pragma unroll
      for (int i = 0; i < 8; ++i) {
        int rowoff = nb + i * 64;
        af[i]  = (short)Kl[rowoff + baseA];
        bf0[i] = (short)Vl[rowoff + baseB0];
        bf1[i] = (short)Vl[rowoff + baseB1];
        bf2[i] = (short)Vl[rowoff + baseB2];
        bf3[i] = (short)Vl[rowoff + baseB3];
      }
      acc[0] = __builtin_amdgcn_mfma_f32_16x16x32_bf16(af, bf0, acc[0], 0, 0, 0);
      acc[1] = __builtin_amdgcn_mfma_f32_16x16x32_bf16(af, bf1, acc[1], 0, 0, 0);
      acc[2] = __builtin_amdgcn_mfma_f32_16x16x32_bf16(af, bf2, acc[2], 0, 0, 0);
      acc[3] = __builtin_amdgcn_mfma_f32_16x16x32_bf16(af, bf3, acc[3], 0, 0, 0);
      ks     = __builtin_amdgcn_mfma_f32_16x16x32_bf16(af, ones, ks, 0, 0, 0);
    }
  }
  float* pp = part + ((size_t)bh * 8 + chunk) * 4096;
  #pragma unroll
  for (int nf = 0; nf < 4; ++nf)
    #pragma unroll
    for (int r = 0; r < 4; ++r)
      pp[(16 * w + 4 * g + r) * 64 + 16 * nf + l15] = acc[nf][r];
  if (l15 == 0) {
    #pragma unroll
    for (int r = 0; r < 4; ++r)
      kspart[((size_t)bh * 8 + chunk) * 64 + 16 * w + 4 * g + r] = ks[r];
  }
}

// ---------------- KV reduce -> KV^T bf16 ([e][d]) + ksum f32 ----------------
__global__ __launch_bounds__(256) void kv_reduce_k(
    const float* __restrict__ part, const float* __restrict__ kspart,
    unsigned short* __restrict__ KVT, float* __restrict__ ksum) {
  int bh = blockIdx.x, t = threadIdx.x;
  for (int idx = t; idx < 4096; idx += 256) {
    int d = idx >> 6, e = idx & 63;
    float s = 0.f;
    #pragma unroll
    for (int c = 0; c < 8; ++c)
      s += part[((size_t)bh * 8 + c) * 4096 + d * 64 + e];
    KVT[(size_t)bh * 4096 + e * 64 + d] = f2bf(s);
  }
  if (t < 64) {
    float s = 0.f;
    #pragma unroll
    for (int c = 0; c < 8; ++c) s += kspart[((size_t)bh * 8 + c) * 64 + t];
    ksum[bh * 64 + t] = s;
  }
}

// ---------------- att = (q' @ KV) * z, written in the reference's reshape ---
__global__ __launch_bounds__(256) void att_k(
    const unsigned short* __restrict__ Qp, const unsigned short* __restrict__ KVT,
    const float* __restrict__ ksum, unsigned short* __restrict__ att) {
  __shared__ unsigned short Ql[128 * 64];
  __shared__ unsigned short Kl[64 * 64];
  __shared__ float ksl[64];
  __shared__ float zl[128];
  int bh = blockIdx.y;
  int b = bh >> 4, h = bh & 15;
  int r0 = blockIdx.x * 128;
  int t = threadIdx.x, lane = t & 63, wid = t >> 6;
  int l15 = lane & 15, lhi = lane >> 4;
  #pragma unroll
  for (int i = 0; i < 4; ++i) {
    int cid = i * 256 + t;
    int r = cid >> 3, c8 = cid & 7;
    gload16(Qp + ((size_t)(b * S_LEN + r0 + r)) * D_MODEL + h * DEPTH + c8 * 8,
            &Ql[cid * 8]);
  }
  #pragma unroll
  for (int i = 0; i < 2; ++i) {
    int cid = i * 256 + t;
    gload16(KVT + (size_t)bh * 4096 + cid * 8, &Kl[cid * 8]);
  }
  if (t < 64) ksl[t] = ksum[bh * 64 + t];
  asm volatile("s_waitcnt vmcnt(0)" ::: "memory");
  __syncthreads();
  {
    int r = t >> 1, half = t & 1;
    float s = 0.f;
    #pragma unroll
    for (int j = 0; j < 32; ++j)
      s += bf2f(Ql[r * 64 + half * 32 + j]) * ksl[half * 32 + j];
    s += __shfl_xor(s, 1);
    if (half == 0) zl[r] = 1.f / (s + EPS_K_F);
  }
  __syncthreads();
  f32x4 acc[2][4] = {};
  #pragma unroll
  for (int kk = 0; kk < 2; ++kk) {
    short8 af[2], bfr[4];
    #pragma unroll
    for (int m = 0; m < 2; ++m)
      af[m] = *(const short8*)&Ql[(wid * 32 + m * 16 + l15) * 64 + kk * 32 + lhi * 8];
    #pragma unroll
    for (int n = 0; n < 4; ++n)
      bfr[n] = *(const short8*)&Kl[(n * 16 + l15) * 64 + kk * 32 + lhi * 8];
    #pragma unroll
    for (int m = 0; m < 2; ++m)
      #pragma unroll
      for (int n = 0; n < 4; ++n)
        acc[m][n] = __builtin_amdgcn_mfma_f32_16x16x32_bf16(af[m], bfr[n], acc[m][n], 0, 0, 0);
  }
  #pragma unroll
  for (int m = 0; m < 2; ++m)
    #pragma unroll
    for (int j = 0; j < 4; ++j) {
      int rl = wid * 32 + m * 16 + lhi * 4 + j;
      int n = r0 + rl;
      float z = zl[rl];
      #pragma unroll
      for (int nf = 0; nf < 4; ++nf) {
        int ee = nf * 16 + l15;
        size_t orow = (size_t)b * S_LEN + h * 256 + (n >> 4);
        int ocol = (n & 15) * 64 + ee;
        att[orow * D_MODEL + ocol] = f2bf(acc[m][nf][j] * z);
      }
    }
}

extern "C" void kernel_launch(void* const* d_in, const int* in_sizes, int n_in,
                              void* d_out, int out_size, void* d_ws, size_t ws_size,
                              hipStream_t stream) {
  (void)in_sizes; (void)n_in; (void)out_size; (void)ws_size;
  const float* q     = (const float*)d_in[0];
  const float* k     = (const float*)d_in[1];
  const float* v     = (const float*)d_in[2];
  const float* mask  = (const float*)d_in[3];
  const float* wq    = (const float*)d_in[4];
  const float* wk    = (const float*)d_in[5];
  const float* wv    = (const float*)d_in[6];
  const float* gamma = (const float*)d_in[7];
  const float* beta  = (const float*)d_in[8];
  const float* dw    = (const float*)d_in[9];
  const float* db    = (const float*)d_in[10];
  float* out = (float*)d_out;

  char* ws = (char*)d_ws;
  unsigned short* Xb  = (unsigned short*)(ws);               // att output (33.5 MB)
  unsigned short* Qp  = (unsigned short*)(ws + 33554432);    // also dense-C after att
  unsigned short* Kp  = (unsigned short*)(ws + 67108864);
  unsigned short* Vp  = (unsigned short*)(ws + 100663296);
  unsigned short* WqT = (unsigned short*)(ws + 134217728);
  unsigned short* WkT = WqT + 1048576;
  unsigned short* WvT = WkT + 1048576;
  unsigned short* WdT = WvT + 1048576;
  float* part   = (float*)(ws);             // aliases Xb (dead until att)
  float* kspart = (float*)(ws + 8388608);
  unsigned short* KVT = (unsigned short*)(ws + 142606336);
  float* ksum = (float*)(ws + 143130624);
  float* psum = (float*)(ws + 143654912);   // 16384*16 f32 = 1 MB
  float* psq  = (float*)(ws + 144703488);   // 1 MB
  unsigned short* Cqkv = (unsigned short*)d_out;   // bf16 C scratch (32 MB of 67)
  unsigned short* Cd   = Qp;                       // dense C: Qp dead after att_k

  dim3 b256(256);
  dim3 b512(512);
  dim3 wtg(32, 32);
  dim3 gemmg(256);            // (M/256)*(N/256), XCD-swizzled in-kernel
  dim3 lng(ROWS);

  wtrans_k<<<wtg, b256, 0, stream>>>(wq, WqT);
  wtrans_k<<<wtg, b256, 0, stream>>>(wk, WkT);
  wtrans_k<<<wtg, b256, 0, stream>>>(wv, WvT);
  wtrans_k<<<wtg, b256, 0, stream>>>(dw, WdT);

  gemm_f32a_k<<<gemmg, b512, 0, stream>>>(q, WqT, Cqkv, psum, psq, ROWS, D_MODEL, D_MODEL);
  ln_act_k<<<lng, b256, 0, stream>>>(Cqkv, psum, psq, gamma, beta, nullptr, Qp, 0);

  gemm_f32a_k<<<gemmg, b512, 0, stream>>>(k, WkT, Cqkv, psum, psq, ROWS, D_MODEL, D_MODEL);
  ln_act_k<<<lng, b256, 0, stream>>>(Cqkv, psum, psq, gamma, beta, mask, Kp, 1);

  gemm_f32a_k<<<gemmg, b512, 0, stream>>>(v, WvT, Cqkv, psum, psq, ROWS, D_MODEL, D_MODEL);
  ln_act_k<<<lng, b256, 0, stream>>>(Cqkv, psum, psq, gamma, beta, mask, Vp, 2);

  kv_mfma_k<<<dim3(8, 64), b256, 0, stream>>>(Kp, Vp, part, kspart);
  kv_reduce_k<<<dim3(64), b256, 0, stream>>>(part, kspart, KVT, ksum);
  att_k<<<dim3(32, 64), b256, 0, stream>>>(Qp, KVT, ksum, Xb);

  gemm_bt_k<<<gemmg, b512, 0, stream>>>(Xb, WdT, Cd, psum, psq, db, ROWS, D_MODEL, D_MODEL);
  ln_final_k<<<lng, b256, 0, stream>>>(Cd, psum, psq, gamma, beta, out);
}

// Round 8
// 352.528 us; speedup vs baseline: 1.1099x; 1.0574x over previous
//
#include <hip/hip_runtime.h>
#include <hip/hip_bf16.h>
#include <stdint.h>

#define D_MODEL 1024
#define S_LEN   4096
#define BATCH   4
#define HEADS   16
#define DEPTH   64
#define ROWS    (BATCH*S_LEN)   // 16384
#define EPS_K_F 1e-6f
#define EPS_LN_F 1e-6f

typedef __attribute__((ext_vector_type(8))) short short8;
typedef __attribute__((ext_vector_type(4))) float f32x4;

__device__ __forceinline__ unsigned short f2bf(float f) {
  union { float f; unsigned u; } x; x.f = f;
  unsigned r = x.u + 0x7FFF + ((x.u >> 16) & 1);
  return (unsigned short)(r >> 16);
}
__device__ __forceinline__ float bf2f(unsigned short b) {
  union { unsigned u; float f; } x; x.u = ((unsigned)b) << 16;
  return x.f;
}
__device__ __forceinline__ void gload16(const void* g, void* l) {
  __builtin_amdgcn_global_load_lds(
      (const __attribute__((address_space(1))) void*)g,
      (__attribute__((address_space(3))) void*)l, 16, 0, 0);
}

// ---------------- f32 -> bf16 convert (q input only) ------------------------
__global__ __launch_bounds__(256) void cvt_f32_bf16_k(
    const float* __restrict__ in, unsigned short* __restrict__ out, int n4) {
  int i = blockIdx.x * 256 + threadIdx.x;
  if (i < n4) {
    float4 v = ((const float4*)in)[i];
    ushort4 o;
    o.x = f2bf(v.x); o.y = f2bf(v.y); o.z = f2bf(v.z); o.w = f2bf(v.w);
    ((ushort4*)out)[i] = o;
  }
}

// ---------------- weight transpose + convert: W[K,N] f32 -> Wt[N,K] bf16 ----
__global__ __launch_bounds__(256) void wtrans_k(
    const float* __restrict__ W, unsigned short* __restrict__ Wt) {
  __shared__ float tile[32][33];
  int n0 = blockIdx.x * 32, k0 = blockIdx.y * 32;
  int tx = threadIdx.x & 31, ty = threadIdx.x >> 5;
  #pragma unroll
  for (int i = 0; i < 32; i += 8)
    tile[ty + i][tx] = W[(size_t)(k0 + ty + i) * D_MODEL + n0 + tx];
  __syncthreads();
  #pragma unroll
  for (int i = 0; i < 32; i += 8)
    Wt[(size_t)(n0 + ty + i) * D_MODEL + k0 + tx] = f2bf(tile[tx][ty + i]);
}

// ===== GEMM: 256x256 tile, 8 waves, BK=64, dbuf LDS, R5 schedule ===========
// + optional "sidecar" f32->bf16 convert of an independent tensor: per block
// 65536 elems, one 4096-elem chunk per K-tile. Chunk c is loaded at tile c-1
// (latency hidden under the whole tile), stored at tile c (store-ack absorbed
// by the existing vmcnt(0) drain). Fills idle memory slots of the drain-bound
// loop; zero impact on the MFMA critical path.
// LDS swizzle: chunk (k>>3) of row r stored at slot (k>>3)^(r&7); frag read
// cx = (kk*4+lhi) ^ (l15&7). Staging keeps LDS linear, inverse-XORs source.
// grid: 256 = (M/256)*(N/256); XCD swizzle cb=(p>>3)&3, rb=(p&7)|((p>>5)<<3).

#define GEMM_EPILOGUE(HASBIAS)                                               \
  if (HASBIAS) {                                                             \
    float bv[4];                                                             \
    _Pragma("unroll")                                                        \
    for (int n = 0; n < 4; ++n)                                              \
      bv[n] = bias[(int)n0 + wcn * 64 + n * 16 + l15];                       \
    _Pragma("unroll")                                                        \
    for (int m = 0; m < 8; ++m)                                              \
      _Pragma("unroll")                                                      \
      for (int n = 0; n < 4; ++n)                                            \
        _Pragma("unroll")                                                    \
        for (int j = 0; j < 4; ++j)                                          \
          acc[m][n][j] += bv[n];                                             \
  }                                                                          \
  int seg = (int)(n0 >> 6) + wcn;                                            \
  _Pragma("unroll")                                                          \
  for (int m = 0; m < 8; ++m) {                                              \
    float s[4], s2[4];                                                       \
    _Pragma("unroll")                                                        \
    for (int j = 0; j < 4; ++j) {                                            \
      float a = 0.f, b = 0.f;                                                \
      _Pragma("unroll")                                                      \
      for (int n = 0; n < 4; ++n) { float x = acc[m][n][j]; a += x; b += x*x; } \
      s[j] = a; s2[j] = b;                                                   \
    }                                                                        \
    _Pragma("unroll")                                                        \
    for (int off = 1; off < 16; off <<= 1) {                                 \
      _Pragma("unroll")                                                      \
      for (int j = 0; j < 4; ++j) {                                          \
        s[j]  += __shfl_xor(s[j],  off);                                     \
        s2[j] += __shfl_xor(s2[j], off);                                     \
      }                                                                      \
    }                                                                        \
    if (l15 == 0) {                                                          \
      _Pragma("unroll")                                                      \
      for (int j = 0; j < 4; ++j) {                                          \
        int rg = (int)m0 + wr * 128 + m * 16 + lhi * 4 + j;                  \
        psum[rg * 16 + seg] = s[j];                                          \
        psq [rg * 16 + seg] = s2[j];                                         \
      }                                                                      \
    }                                                                        \
  }                                                                          \
  _Pragma("unroll")                                                          \
  for (int m = 0; m < 8; ++m)                                                \
    _Pragma("unroll")                                                        \
    for (int j = 0; j < 4; ++j) {                                            \
      size_t row = m0 + wr * 128 + m * 16 + lhi * 4 + j;                     \
      _Pragma("unroll")                                                      \
      for (int n = 0; n < 4; ++n) {                                          \
        int col = (int)n0 + wcn * 64 + n * 16 + l15;                         \
        Cb[row * N + col] = f2bf(acc[m][n][j]);                              \
      }                                                                      \
    }

#define GEMM_COMPUTE_TILE(ABUF, BBUF)                                        \
  _Pragma("unroll")                                                          \
  for (int kk = 0; kk < 2; ++kk) {                                           \
    short8 bfr[4];                                                           \
    _Pragma("unroll")                                                        \
    for (int n = 0; n < 4; ++n) {                                            \
      int rr = wcn * 64 + n * 16 + l15;                                      \
      int cx = (kk * 4 + lhi) ^ (l15 & 7);                                   \
      bfr[n] = *(const short8*)&(BBUF)[rr * 64 + cx * 8];                    \
    }                                                                        \
    _Pragma("unroll")                                                        \
    for (int mh = 0; mh < 2; ++mh) {                                         \
      short8 af[4];                                                          \
      _Pragma("unroll")                                                      \
      for (int m = 0; m < 4; ++m) {                                          \
        int rr = wr * 128 + (mh * 4 + m) * 16 + l15;                         \
        int cx = (kk * 4 + lhi) ^ (l15 & 7);                                 \
        af[m] = *(const short8*)&(ABUF)[rr * 64 + cx * 8];                   \
      }                                                                      \
      asm volatile("s_waitcnt lgkmcnt(0)" ::: "memory");                     \
      __builtin_amdgcn_sched_barrier(0);                                     \
      __builtin_amdgcn_s_setprio(1);                                         \
      _Pragma("unroll")                                                      \
      for (int m = 0; m < 4; ++m)                                            \
        _Pragma("unroll")                                                    \
        for (int n = 0; n < 4; ++n)                                          \
          acc[mh * 4 + m][n] = __builtin_amdgcn_mfma_f32_16x16x32_bf16(      \
              af[m], bfr[n], acc[mh * 4 + m][n], 0, 0, 0);                   \
      __builtin_amdgcn_s_setprio(0);                                         \
    }                                                                        \
  }

__global__ __launch_bounds__(512, 2) void gemm_bt_k(
    const unsigned short* __restrict__ A,
    const unsigned short* __restrict__ Bt,
    unsigned short* __restrict__ Cb,
    float* __restrict__ psum, float* __restrict__ psq,
    const float* __restrict__ bias,
    const float* __restrict__ side_src,      // optional f32 tensor to convert
    unsigned short* __restrict__ side_dst,   // nullptr = no sidecar
    int M, int N, int K) {
  __shared__ unsigned short Al[2][256 * 64];
  __shared__ unsigned short Bl[2][256 * 64];
  int t = threadIdx.x;
  int lane = t & 63, wid = t >> 6;
  int wr = wid >> 2, wcn = wid & 3;
  int l15 = lane & 15, lhi = lane >> 4;
  int p = blockIdx.x;
  int cb = (p >> 3) & 3;
  int rb = (p & 7) | ((p >> 5) << 3);
  size_t m0 = (size_t)rb * 256, n0 = (size_t)cb * 256;
  f32x4 acc[8][4] = {};

  const int KT = K >> 6;                  // 16 K-tiles of 64 (K==1024 here)

#define STAGE_AB(kof_, buf_) do {                                            \
    _Pragma("unroll")                                                        \
    for (int sub = 0; sub < 4; ++sub) {                                      \
      int idx = sub * 512 + t; int r_ = idx >> 3, cl_ = idx & 7;             \
      int cg_ = cl_ ^ (r_ & 7);                                              \
      gload16(A + (m0 + r_) * (size_t)K + (kof_) + cg_ * 8,                  \
              &Al[buf_][idx * 8]);                                           \
    }                                                                        \
    _Pragma("unroll")                                                        \
    for (int sub = 0; sub < 4; ++sub) {                                      \
      int idx = sub * 512 + t; int r_ = idx >> 3, cl_ = idx & 7;             \
      int cg_ = cl_ ^ (r_ & 7);                                              \
      gload16(Bt + (n0 + r_) * (size_t)K + (kof_) + cg_ * 8,                 \
              &Bl[buf_][idx * 8]);                                           \
    }                                                                        \
  } while (0)

  // sidecar state: this block converts elems [p*65536, (p+1)*65536)
  float4 sreg0 = {}, sreg1 = {};
  size_t sbase = (size_t)p * 65536 + (size_t)t * 8;

  STAGE_AB(0, 0);
  if (side_dst) {                          // load chunk 0
    sreg0 = *(const float4*)(side_src + sbase);
    sreg1 = *(const float4*)(side_src + sbase + 4);
  }
  asm volatile("s_waitcnt vmcnt(0)" ::: "memory");
  __builtin_amdgcn_s_barrier();
  __builtin_amdgcn_sched_barrier(0);

  for (int kt = 0; kt < KT; ++kt) {
    int buf = kt & 1;
    if (kt + 1 < KT) STAGE_AB((kt + 1) << 6, buf ^ 1);
    if (side_dst) {
      // store chunk kt (loaded one tile ago; long since arrived)
      uint4 pk;
      pk.x = (unsigned)f2bf(sreg0.x) | ((unsigned)f2bf(sreg0.y) << 16);
      pk.y = (unsigned)f2bf(sreg0.z) | ((unsigned)f2bf(sreg0.w) << 16);
      pk.z = (unsigned)f2bf(sreg1.x) | ((unsigned)f2bf(sreg1.y) << 16);
      pk.w = (unsigned)f2bf(sreg1.z) | ((unsigned)f2bf(sreg1.w) << 16);
      *(uint4*)(side_dst + sbase + (size_t)kt * 4096) = pk;
      if (kt + 1 < KT) {                   // issue loads for chunk kt+1
        const float* sp = side_src + sbase + (size_t)(kt + 1) * 4096;
        sreg0 = *(const float4*)sp;
        sreg1 = *(const float4*)(sp + 4);
      }
    }
    __builtin_amdgcn_sched_barrier(0);
    GEMM_COMPUTE_TILE(Al[buf], Bl[buf]);
    asm volatile("s_waitcnt vmcnt(0) lgkmcnt(0)" ::: "memory");
    __builtin_amdgcn_s_barrier();
    __builtin_amdgcn_sched_barrier(0);
  }
#undef STAGE_AB

  GEMM_EPILOGUE(bias != nullptr)
}

// ---------------- LN + activation from bf16 C + partials -> bf16 ------------
// mode 0: relu(ln)+eps ; mode 1: (relu(ln)+eps)*mask ; mode 2: ln*mask
__global__ __launch_bounds__(256) void ln_act_k(
    const unsigned short* __restrict__ Cb,
    const float* __restrict__ psum, const float* __restrict__ psq,
    const float* __restrict__ gamma, const float* __restrict__ beta,
    const float* __restrict__ mask,
    unsigned short* __restrict__ out, int mode) {
  int row = blockIdx.x;
  int t = threadIdx.x;
  float s = 0.f, s2 = 0.f;
  #pragma unroll
  for (int i = 0; i < 16; ++i) { s += psum[row * 16 + i]; s2 += psq[row * 16 + i]; }
  float mean = s * (1.f / D_MODEL);
  float var = s2 * (1.f / D_MODEL) - mean * mean;
  float rstd = rsqrtf(var + EPS_LN_F);
  float mk = (mode > 0) ? mask[row] : 1.f;
  ushort4 cv = ((const ushort4*)(Cb + (size_t)row * D_MODEL))[t];
  float4 gv = ((const float4*)gamma)[t];
  float4 bv = ((const float4*)beta)[t];
  float av[4] = {bf2f(cv.x), bf2f(cv.y), bf2f(cv.z), bf2f(cv.w)};
  float g4[4] = {gv.x, gv.y, gv.z, gv.w};
  float b4[4] = {bv.x, bv.y, bv.z, bv.w};
  unsigned short ov[4];
  #pragma unroll
  for (int j = 0; j < 4; ++j) {
    float ln = (av[j] - mean) * rstd * g4[j] + b4[j];
    if (mode == 0)      ln = fmaxf(ln, 0.f) + EPS_K_F;
    else if (mode == 1) ln = (fmaxf(ln, 0.f) + EPS_K_F) * mk;
    else                ln = ln * mk;
    ov[j] = f2bf(ln);
  }
  ushort4 o; o.x = ov[0]; o.y = ov[1]; o.z = ov[2]; o.w = ov[3];
  ((ushort4*)(out + (size_t)row * D_MODEL))[t] = o;
}

// ---------------- final LayerNorm from bf16 C + partials -> f32 out ---------
__global__ __launch_bounds__(256) void ln_final_k(
    const unsigned short* __restrict__ Cb,
    const float* __restrict__ psum, const float* __restrict__ psq,
    const float* __restrict__ gamma, const float* __restrict__ beta,
    float* __restrict__ out) {
  int row = blockIdx.x;
  int t = threadIdx.x;
  float s = 0.f, s2 = 0.f;
  #pragma unroll
  for (int i = 0; i < 16; ++i) { s += psum[row * 16 + i]; s2 += psq[row * 16 + i]; }
  float mean = s * (1.f / D_MODEL);
  float var = s2 * (1.f / D_MODEL) - mean * mean;
  float rstd = rsqrtf(var + EPS_LN_F);
  ushort4 cv = ((const ushort4*)(Cb + (size_t)row * D_MODEL))[t];
  float4 gv = ((const float4*)gamma)[t];
  float4 bv = ((const float4*)beta)[t];
  float4 w;
  w.x = (bf2f(cv.x) - mean) * rstd * gv.x + bv.x;
  w.y = (bf2f(cv.y) - mean) * rstd * gv.y + bv.y;
  w.z = (bf2f(cv.z) - mean) * rstd * gv.z + bv.z;
  w.w = (bf2f(cv.w) - mean) * rstd * gv.w + bv.w;
  ((float4*)(out + (size_t)row * D_MODEL))[t] = w;
}

// ---------------- KV via MFMA with swizzled-LDS transpose -------------------
__global__ __launch_bounds__(256) void kv_mfma_k(
    const unsigned short* __restrict__ Kp, const unsigned short* __restrict__ Vp,
    float* __restrict__ part, float* __restrict__ kspart) {
  __shared__ unsigned short Kl[4096];
  __shared__ unsigned short Vl[4096];
  int bh = blockIdx.y, chunk = blockIdx.x;   // chunk 0..7, 512 n each
  int b_ = bh >> 4, h = bh & 15;
  int t = threadIdx.x, lane = t & 63, w = t >> 6;
  int l15 = lane & 15, g = lane >> 4;        // g in 0..3

  int sn = t >> 2, sd16 = t & 3;
  int sc = sd16 ^ ((sn >> 3) & 3);
  size_t goff = (size_t)sn * D_MODEL + h * DEPTH + sd16 * 16;
  int ldst = sn * 64 + sc * 16;

  short8 ones;
  #pragma unroll
  for (int i = 0; i < 8; ++i) ones[i] = (short)0x3F80;

  f32x4 acc[4] = {};
  f32x4 ks = {};

  int baseA = ((w ^ g) << 4) + l15;
  int baseB0 = ((0 ^ g) << 4) + l15;
  int baseB1 = ((1 ^ g) << 4) + l15;
  int baseB2 = ((2 ^ g) << 4) + l15;
  int baseB3 = ((3 ^ g) << 4) + l15;

  size_t rowbase = ((size_t)b_ * S_LEN + (size_t)chunk * 512) * D_MODEL;
  for (int tile = 0; tile < 8; ++tile) {
    const unsigned short* kg = Kp + rowbase + (size_t)tile * 64 * D_MODEL + goff;
    const unsigned short* vg = Vp + rowbase + (size_t)tile * 64 * D_MODEL + goff;
    uint4 ra = *(const uint4*)kg;
    uint4 rb = *(const uint4*)(kg + 8);
    uint4 rc = *(const uint4*)vg;
    uint4 rd = *(const uint4*)(vg + 8);
    __syncthreads();
    *(uint4*)&Kl[ldst]     = ra;
    *(uint4*)&Kl[ldst + 8] = rb;
    *(uint4*)&Vl[ldst]     = rc;
    *(uint4*)&Vl[ldst + 8] = rd;
    __syncthreads();
    #pragma unroll
    for (int kk = 0; kk < 2; ++kk) {
      int nb = (kk * 32 + g * 8) * 64;
      short8 af, bf0, bf1, bf2, bf3;
      #pragma unroll
      for (int i = 0; i < 8; ++i) {
        int rowoff = nb + i * 64;
        af[i]  = (short)Kl[rowoff + baseA];
        bf0[i] = (short)Vl[rowoff + baseB0];
        bf1[i] = (short)Vl[rowoff + baseB1];
        bf2[i] = (short)Vl[rowoff + baseB2];
        bf3[i] = (short)Vl[rowoff + baseB3];
      }
      acc[0] = __builtin_amdgcn_mfma_f32_16x16x32_bf16(af, bf0, acc[0], 0, 0, 0);
      acc[1] = __builtin_amdgcn_mfma_f32_16x16x32_bf16(af, bf1, acc[1], 0, 0, 0);
      acc[2] = __builtin_amdgcn_mfma_f32_16x16x32_bf16(af, bf2, acc[2], 0, 0, 0);
      acc[3] = __builtin_amdgcn_mfma_f32_16x16x32_bf16(af, bf3, acc[3], 0, 0, 0);
      ks     = __builtin_amdgcn_mfma_f32_16x16x32_bf16(af, ones, ks, 0, 0, 0);
    }
  }
  float* pp = part + ((size_t)bh * 8 + chunk) * 4096;
  #pragma unroll
  for (int nf = 0; nf < 4; ++nf)
    #pragma unroll
    for (int r = 0; r < 4; ++r)
      pp[(16 * w + 4 * g + r) * 64 + 16 * nf + l15] = acc[nf][r];
  if (l15 == 0) {
    #pragma unroll
    for (int r = 0; r < 4; ++r)
      kspart[((size_t)bh * 8 + chunk) * 64 + 16 * w + 4 * g + r] = ks[r];
  }
}

// ---------------- KV reduce -> KV^T bf16 ([e][d]) + ksum f32 ----------------
__global__ __launch_bounds__(256) void kv_reduce_k(
    const float* __restrict__ part, const float* __restrict__ kspart,
    unsigned short* __restrict__ KVT, float* __restrict__ ksum) {
  int bh = blockIdx.x, t = threadIdx.x;
  for (int idx = t; idx < 4096; idx += 256) {
    int d = idx >> 6, e = idx & 63;
    float s = 0.f;
    #pragma unroll
    for (int c = 0; c < 8; ++c)
      s += part[((size_t)bh * 8 + c) * 4096 + d * 64 + e];
    KVT[(size_t)bh * 4096 + e * 64 + d] = f2bf(s);
  }
  if (t < 64) {
    float s = 0.f;
    #pragma unroll
    for (int c = 0; c < 8; ++c) s += kspart[((size_t)bh * 8 + c) * 64 + t];
    ksum[bh * 64 + t] = s;
  }
}

// ---------------- att = (q' @ KV) * z, written in the reference's reshape ---
__global__ __launch_bounds__(256) void att_k(
    const unsigned short* __restrict__ Qp, const unsigned short* __restrict__ KVT,
    const float* __restrict__ ksum, unsigned short* __restrict__ att) {
  __shared__ unsigned short Ql[128 * 64];
  __shared__ unsigned short Kl[64 * 64];
  __shared__ float ksl[64];
  __shared__ float zl[128];
  int bh = blockIdx.y;
  int b = bh >> 4, h = bh & 15;
  int r0 = blockIdx.x * 128;
  int t = threadIdx.x, lane = t & 63, wid = t >> 6;
  int l15 = lane & 15, lhi = lane >> 4;
  #pragma unroll
  for (int i = 0; i < 4; ++i) {
    int cid = i * 256 + t;
    int r = cid >> 3, c8 = cid & 7;
    gload16(Qp + ((size_t)(b * S_LEN + r0 + r)) * D_MODEL + h * DEPTH + c8 * 8,
            &Ql[cid * 8]);
  }
  #pragma unroll
  for (int i = 0; i < 2; ++i) {
    int cid = i * 256 + t;
    gload16(KVT + (size_t)bh * 4096 + cid * 8, &Kl[cid * 8]);
  }
  if (t < 64) ksl[t] = ksum[bh * 64 + t];
  asm volatile("s_waitcnt vmcnt(0)" ::: "memory");
  __syncthreads();
  {
    int r = t >> 1, half = t & 1;
    float s = 0.f;
    #pragma unroll
    for (int j = 0; j < 32; ++j)
      s += bf2f(Ql[r * 64 + half * 32 + j]) * ksl[half * 32 + j];
    s += __shfl_xor(s, 1);
    if (half == 0) zl[r] = 1.f / (s + EPS_K_F);
  }
  __syncthreads();
  f32x4 acc[2][4] = {};
  #pragma unroll
  for (int kk = 0; kk < 2; ++kk) {
    short8 af[2], bfr[4];
    #pragma unroll
    for (int m = 0; m < 2; ++m)
      af[m] = *(const short8*)&Ql[(wid * 32 + m * 16 + l15) * 64 + kk * 32 + lhi * 8];
    #pragma unroll
    for (int n = 0; n < 4; ++n)
      bfr[n] = *(const short8*)&Kl[(n * 16 + l15) * 64 + kk * 32 + lhi * 8];
    #pragma unroll
    for (int m = 0; m < 2; ++m)
      #pragma unroll
      for (int n = 0; n < 4; ++n)
        acc[m][n] = __builtin_amdgcn_mfma_f32_16x16x32_bf16(af[m], bfr[n], acc[m][n], 0, 0, 0);
  }
  #pragma unroll
  for (int m = 0; m < 2; ++m)
    #pragma unroll
    for (int j = 0; j < 4; ++j) {
      int rl = wid * 32 + m * 16 + lhi * 4 + j;
      int n = r0 + rl;
      float z = zl[rl];
      #pragma unroll
      for (int nf = 0; nf < 4; ++nf) {
        int ee = nf * 16 + l15;
        size_t orow = (size_t)b * S_LEN + h * 256 + (n >> 4);
        int ocol = (n & 15) * 64 + ee;
        att[orow * D_MODEL + ocol] = f2bf(acc[m][nf][j] * z);
      }
    }
}

extern "C" void kernel_launch(void* const* d_in, const int* in_sizes, int n_in,
                              void* d_out, int out_size, void* d_ws, size_t ws_size,
                              hipStream_t stream) {
  (void)in_sizes; (void)n_in; (void)out_size; (void)ws_size;
  const float* q     = (const float*)d_in[0];
  const float* k     = (const float*)d_in[1];
  const float* v     = (const float*)d_in[2];
  const float* mask  = (const float*)d_in[3];
  const float* wq    = (const float*)d_in[4];
  const float* wk    = (const float*)d_in[5];
  const float* wv    = (const float*)d_in[6];
  const float* gamma = (const float*)d_in[7];
  const float* beta  = (const float*)d_in[8];
  const float* dw    = (const float*)d_in[9];
  const float* db    = (const float*)d_in[10];
  float* out = (float*)d_out;

  char* ws = (char*)d_ws;
  // buffer plan (lifetimes hand-verified):
  //   bufA @0      : Xq (cvt) -> consumed by gemm_q; then Xv (gemm_k sidecar)
  //                  -> consumed by gemm_v; then part/att scratch.
  //   Qp  @32MB    : q' (ln_act) -> consumed by att; then dense-C.
  //   bufB @64MB   : Xk (gemm_q sidecar) -> consumed by gemm_k; then Kp (ln_act).
  //   Vp  @96MB    : v' (ln_act) -> consumed by kv_mfma.
  unsigned short* bufA = (unsigned short*)(ws);
  unsigned short* Qp   = (unsigned short*)(ws + 33554432);
  unsigned short* bufB = (unsigned short*)(ws + 67108864);
  unsigned short* Kp   = bufB;
  unsigned short* Vp   = (unsigned short*)(ws + 100663296);
  unsigned short* WqT  = (unsigned short*)(ws + 134217728);
  unsigned short* WkT = WqT + 1048576;
  unsigned short* WvT = WkT + 1048576;
  unsigned short* WdT = WvT + 1048576;
  float* part   = (float*)(ws);             // aliases bufA (dead by then)
  float* kspart = (float*)(ws + 8388608);
  unsigned short* KVT = (unsigned short*)(ws + 142606336);
  float* ksum = (float*)(ws + 143130624);
  float* psum = (float*)(ws + 143654912);   // 16384*16 f32 = 1 MB
  float* psq  = (float*)(ws + 144703488);   // 1 MB
  unsigned short* Cqkv = (unsigned short*)d_out;   // bf16 C scratch (32 of 67 MB)
  unsigned short* Cd   = Qp;                       // dense C: Qp dead after att_k

  dim3 b256(256);
  dim3 b512(512);
  int n4 = ROWS * D_MODEL / 4;
  dim3 cvtg(n4 / 256);
  dim3 wtg(32, 32);
  dim3 gemmg(256);            // (M/256)*(N/256), XCD-swizzled in-kernel
  dim3 lng(ROWS);

  wtrans_k<<<wtg, b256, 0, stream>>>(wq, WqT);
  wtrans_k<<<wtg, b256, 0, stream>>>(wk, WkT);
  wtrans_k<<<wtg, b256, 0, stream>>>(wv, WvT);
  wtrans_k<<<wtg, b256, 0, stream>>>(dw, WdT);

  cvt_f32_bf16_k<<<cvtg, b256, 0, stream>>>(q, bufA, n4);

  // gemm_q: A = Xq (bufA); sidecar converts k -> bufB
  gemm_bt_k<<<gemmg, b512, 0, stream>>>(bufA, WqT, Cqkv, psum, psq, nullptr,
                                        k, bufB, ROWS, D_MODEL, D_MODEL);
  ln_act_k<<<lng, b256, 0, stream>>>(Cqkv, psum, psq, gamma, beta, nullptr, Qp, 0);

  // gemm_k: A = Xk (bufB); sidecar converts v -> bufA
  gemm_bt_k<<<gemmg, b512, 0, stream>>>(bufB, WkT, Cqkv, psum, psq, nullptr,
                                        v, bufA, ROWS, D_MODEL, D_MODEL);
  ln_act_k<<<lng, b256, 0, stream>>>(Cqkv, psum, psq, gamma, beta, mask, Kp, 1);

  // gemm_v: A = Xv (bufA); no sidecar
  gemm_bt_k<<<gemmg, b512, 0, stream>>>(bufA, WvT, Cqkv, psum, psq, nullptr,
                                        nullptr, nullptr, ROWS, D_MODEL, D_MODEL);
  ln_act_k<<<lng, b256, 0, stream>>>(Cqkv, psum, psq, gamma, beta, mask, Vp, 2);

  kv_mfma_k<<<dim3(8, 64), b256, 0, stream>>>(Kp, Vp, part, kspart);
  kv_reduce_k<<<dim3(64), b256, 0, stream>>>(part, kspart, KVT, ksum);
  att_k<<<dim3(32, 64), b256, 0, stream>>>(Qp, KVT, ksum, bufA);

  gemm_bt_k<<<gemmg, b512, 0, stream>>>(bufA, WdT, Cd, psum, psq, db,
                                        nullptr, nullptr, ROWS, D_MODEL, D_MODEL);
  ln_final_k<<<lng, b256, 0, stream>>>(Cd, psum, psq, gamma, beta, out);
}